// Round 5
// baseline (228.733 us; speedup 1.0000x reference)
//
#include <hip/hip_runtime.h>
#include <hip/hip_bf16.h>
#include <cstdint>
#include <cstddef>

// LSTM fused pipeline, round 3.
// - cell fused into GEMM epilogue via gate-interleaved layout (j = 4n + gate)
// - combo dispatches: fused1(t) [K=2048] || fused0(t+1) [K=1024] -> 512 blocks, 2/CU
// - Gz0R = z @ W_ih0R^T + bias0R precomputed once (z constant across steps)
// - 2-phase double-buffered GEMM core, LDS swizzle via pre-swizzled global source

typedef __bf16 bf16_t;
typedef __bf16 bf16x8 __attribute__((ext_vector_type(8)));
typedef __bf16 bf16x4 __attribute__((ext_vector_type(4)));
typedef float f32x4 __attribute__((ext_vector_type(4)));

__device__ __forceinline__ void gload_lds16(const bf16_t* g, bf16_t* l) {
    __builtin_amdgcn_global_load_lds(
        (const __attribute__((address_space(1))) void*)g,
        (__attribute__((address_space(3))) void*)l,
        16, 0, 0);
}

__device__ __forceinline__ float sigmoid_f(float x) {
    return 1.f / (1.f + __expf(-x));
}
__device__ __forceinline__ float tanh_fast(float x) {
    const float t = __expf(2.f * x);
    return 1.f - 2.f / (t + 1.f);
}

// Shared GEMM core: C_tile(128x128) = A[brow:+128, :K] @ B[bcol:+128, :K]^T.
// block = 512 (8 waves, 2x4), wave = 64x32 = 4x2 frags. lsA/lsB: 2 bufs x 8192 bf16 each.
__device__ __forceinline__ void gemm_core(
    const bf16_t* __restrict__ A, int lda,
    const bf16_t* __restrict__ B, int ldb,
    int K, int brow, int bcol,
    bf16_t* lsA, bf16_t* lsB, f32x4 acc[4][2])
{
    const int tid  = threadIdx.x;
    const int lane = tid & 63;
    const int wave = tid >> 6;
    const int wm = (wave >> 2) * 64;
    const int wn = (wave & 3) * 32;
    const int srow = lane >> 3;                  // 0..7
    const int ssw  = ((lane & 7) ^ srow) * 8;    // pre-swizzled source col (rule #21)
    const int ch0  = wave * 2;
    const int nkt  = K >> 6;

    auto stage = [&](int buf, int ktel) {
#pragma unroll
        for (int it = 0; it < 2; ++it) {
            const int ch = ch0 + it;
            const int row = ch * 8 + srow;
            gload_lds16(A + (size_t)(brow + row) * lda + ktel + ssw, &lsA[buf * 8192 + ch * 512]);
            gload_lds16(B + (size_t)(bcol + row) * ldb + ktel + ssw, &lsB[buf * 8192 + ch * 512]);
        }
    };

    stage(0, 0);
    __syncthreads();

    const int fr  = lane & 15;
    const int g8  = (lane >> 4) * 8;
    const int rsw = (fr & 7) * 8;                // read-side swizzle XOR (elems)

    for (int kt = 0; kt < nkt; ++kt) {
        const int buf = kt & 1;
        if (kt + 1 < nkt) stage(buf ^ 1, (kt + 1) << 6);   // prefetch BEFORE compute
#pragma unroll
        for (int kk = 0; kk < 2; ++kk) {
            const int ko = (kk * 32 + g8) ^ rsw;
            bf16x8 af[4], bfv[2];
#pragma unroll
            for (int m = 0; m < 4; ++m)
                af[m] = *(const bf16x8*)&lsA[buf * 8192 + (wm + m * 16 + fr) * 64 + ko];
#pragma unroll
            for (int n = 0; n < 2; ++n)
                bfv[n] = *(const bf16x8*)&lsB[buf * 8192 + (wn + n * 16 + fr) * 64 + ko];
#pragma unroll
            for (int m = 0; m < 4; ++m)
#pragma unroll
                for (int n = 0; n < 2; ++n)
                    acc[m][n] = __builtin_amdgcn_mfma_f32_16x16x32_bf16(af[m], bfv[n], acc[m][n], 0, 0, 0);
        }
        __syncthreads();   // drains prefetch vmcnt + protects LDS
    }
}

// ---- plain GEMM (Gz0 + output linear): C = A@B^T + bias, f32 out ----
__global__ __launch_bounds__(512) void gemm_bf16_nt(
    const bf16_t* __restrict__ A, int lda, size_t sAz,
    const bf16_t* __restrict__ B, int ldb,
    const float* __restrict__ bias,
    float* __restrict__ C, int ldc, int czoff, int K)
{
    __shared__ __align__(16) bf16_t ls[32768];
    f32x4 acc[4][2] = {};
    const int brow = blockIdx.y * 128;
    const int bcol = blockIdx.x * 128;
    gemm_core(A + (size_t)blockIdx.z * sAz, lda, B, ldb, K, brow, bcol, ls, ls + 16384, acc);

    const int lane = threadIdx.x & 63;
    const int wave = threadIdx.x >> 6;
    const int wm = (wave >> 2) * 64;
    const int wn = (wave & 3) * 32;
    const int cr = (lane >> 4) * 4;
    const int cc = lane & 15;
    const size_t colz = (size_t)blockIdx.z * czoff;
#pragma unroll
    for (int n = 0; n < 2; ++n) {
        const int col = bcol + wn + n * 16 + cc;
        const float bv = bias ? bias[col] : 0.f;
#pragma unroll
        for (int m = 0; m < 4; ++m) {
            const int row0 = brow + wm + m * 16 + cr;
#pragma unroll
            for (int r = 0; r < 4; ++r)
                C[(size_t)(row0 + r) * ldc + colz + col] = acc[m][n][r] + bv;
        }
    }
}

// ---- fused GEMM + LSTM cell (gate-interleaved layout j = 4n + gate) ----
struct FusedArgs {
    const bf16_t* A;       // [1024][lda]
    const bf16_t* B;       // [4096][K] reordered rows
    const float*  add;     // f32 [1024][4096] reordered (Gz0R) or null
    const float*  biasR;   // f32 [4096] reordered or null
    float*        c;       // f32 [1024][1024] cell state (in/out)
    bf16_t*       h1; int h1s;   // h dest 1 (stride in elems)
    bf16_t*       h2; int h2s;   // h dest 2 or null
    int K; int lda;
};

__global__ __launch_bounds__(512, 4) void fused_gemm_cell(FusedArgs fa0, FusedArgs fa1)
{
    __shared__ __align__(16) float gsm[16384];   // 64KB: staging (bf16) then gates (f32)
    const FusedArgs fa = blockIdx.z ? fa1 : fa0;
    const int brow = blockIdx.y * 128;
    const int bcol = blockIdx.x * 128;

    f32x4 acc[4][2] = {};
    bf16_t* ls = (bf16_t*)gsm;
    gemm_core(fa.A, fa.lda, fa.B, fa.K, fa.K, brow, bcol, ls, ls + 16384, acc);
    // core ends with __syncthreads() and drained vmcnt -> LDS reusable

    const int tid  = threadIdx.x;
    const int lane = tid & 63;
    const int wave = tid >> 6;
    const int wm = (wave >> 2) * 64;
    const int wn = (wave & 3) * 32;
    const int cr = (lane >> 4) * 4;
    const int cc = lane & 15;
#pragma unroll
    for (int n = 0; n < 2; ++n)
#pragma unroll
        for (int m = 0; m < 4; ++m)
#pragma unroll
            for (int r = 0; r < 4; ++r)
                gsm[(wm + m * 16 + cr + r) * 128 + wn + n * 16 + cc] = acc[m][n][r];
    __syncthreads();

    // cell: 4096 (row, n) pairs, 8 per thread; gates at [row][4nn .. 4nn+3]
#pragma unroll
    for (int p = 0; p < 8; ++p) {
        const int idx = p * 512 + tid;
        const int rl = idx >> 5;          // 0..127
        const int nn = idx & 31;          // 0..31
        float4 gv = *(const float4*)&gsm[rl * 128 + nn * 4];
        const int grow = brow + rl;
        const int j0 = bcol + nn * 4;
        if (fa.add) {
            const float4 av = *(const float4*)&fa.add[(size_t)grow * 4096 + j0];
            gv.x += av.x; gv.y += av.y; gv.z += av.z; gv.w += av.w;
        }
        if (fa.biasR) {
            const float4 bv = *(const float4*)&fa.biasR[j0];
            gv.x += bv.x; gv.y += bv.y; gv.z += bv.z; gv.w += bv.w;
        }
        const int ng = j0 >> 2;           // global n
        const size_t ci = (size_t)grow * 1024 + ng;
        const float cn = sigmoid_f(gv.y) * fa.c[ci] + sigmoid_f(gv.x) * tanh_fast(gv.z);
        const float h  = sigmoid_f(gv.w) * tanh_fast(cn);
        fa.c[ci] = cn;
        const bf16_t hb = (bf16_t)h;
        fa.h1[(size_t)grow * fa.h1s + ng] = hb;
        if (fa.h2) fa.h2[(size_t)grow * fa.h2s + ng] = hb;
    }
}

// ---- prep kernels ----

// plain f32 -> bf16 (W_lin)
__global__ __launch_bounds__(256) void conv_f32_bf16(
    const float4* __restrict__ in, bf16x4* __restrict__ out)
{
    const int t = blockIdx.x * 256 + threadIdx.x;
    const float4 a = in[t];
    bf16x4 v = {(bf16_t)a.x, (bf16_t)a.y, (bf16_t)a.z, (bf16_t)a.w};
    out[t] = v;
}

// f32 [4096][1024] -> bf16 with row reorder j=4n+g <- g*1024+n
__global__ __launch_bounds__(256) void convR_f32_bf16(
    const float4* __restrict__ in, bf16x4* __restrict__ out)
{
    const int tid = blockIdx.x * 256 + threadIdx.x;   // 4096*256
    const int j = tid >> 8;
    const int col = tid & 255;
    const int g = j & 3, n = j >> 2;
    const float4 a = in[(g * 1024 + n) * 256 + col];
    bf16x4 v = {(bf16_t)a.x, (bf16_t)a.y, (bf16_t)a.z, (bf16_t)a.w};
    out[tid] = v;
}

// WcatR[4096][2048] = [W_ih1 | W_hh1] reordered rows j=4n+g
__global__ __launch_bounds__(256) void prep_wcatR(
    const float4* __restrict__ Wih, const float4* __restrict__ Whh, bf16x4* __restrict__ Wcat)
{
    const int tid = blockIdx.x * 256 + threadIdx.x;   // 4096*256
    const int j = tid >> 8;
    const int col = tid & 255;
    const int g = j & 3, n = j >> 2;
    const int src = (g * 1024 + n) * 256 + col;
    const float4 a = Wih[src];
    const float4 b = Whh[src];
    bf16x4 va = {(bf16_t)a.x, (bf16_t)a.y, (bf16_t)a.z, (bf16_t)a.w};
    bf16x4 vb = {(bf16_t)b.x, (bf16_t)b.y, (bf16_t)b.z, (bf16_t)b.w};
    Wcat[j * 512 + col]       = va;
    Wcat[j * 512 + 256 + col] = vb;
}

__global__ __launch_bounds__(256) void prep_biasR(
    const float* __restrict__ bih0, const float* __restrict__ bhh0,
    const float* __restrict__ bih1, const float* __restrict__ bhh1,
    float* __restrict__ b0R, float* __restrict__ b1R)
{
    const int j = blockIdx.x * 256 + threadIdx.x;     // 4096
    const int g = j & 3, n = j >> 2;
    b0R[j] = bih0[g * 1024 + n] + bhh0[g * 1024 + n];
    b1R[j] = bih1[g * 1024 + n] + bhh1[g * 1024 + n];
}

// zb = bf16(z); X0 h-slot = bf16(z); c0 = c1 = z
__global__ __launch_bounds__(256) void prep_init(
    const float* __restrict__ z, bf16_t* __restrict__ zb,
    bf16_t* __restrict__ X0, float* __restrict__ c0, float* __restrict__ c1)
{
    const int tid = blockIdx.x * 256 + threadIdx.x;   // 1M
    const int b = tid >> 10;
    const int n = tid & 1023;
    const float v = z[tid];
    const bf16_t h = (bf16_t)v;
    zb[tid] = h;
    X0[(size_t)b * 2048 + 1024 + n] = h;
    c0[tid] = v;
    c1[tid] = v;
}

extern "C" void kernel_launch(void* const* d_in, const int* in_sizes, int n_in,
                              void* d_out, int out_size, void* d_ws, size_t ws_size,
                              hipStream_t stream)
{
    const float* z     = (const float*)d_in[0];
    const float* W_ih0 = (const float*)d_in[1];
    const float* W_hh0 = (const float*)d_in[2];
    const float* b_ih0 = (const float*)d_in[3];
    const float* b_hh0 = (const float*)d_in[4];
    const float* W_ih1 = (const float*)d_in[5];
    const float* W_hh1 = (const float*)d_in[6];
    const float* b_ih1 = (const float*)d_in[7];
    const float* b_hh1 = (const float*)d_in[8];
    const float* W_lin = (const float*)d_in[9];
    const float* b_lin = (const float*)d_in[10];
    float* out = (float*)d_out;

    char* ws = (char*)d_ws;
    const size_t MB = 1u << 20;
    bf16_t* WcatR1 = (bf16_t*)(ws);               // 16MB  [4096][2048]
    bf16_t* Whh0R  = (bf16_t*)(ws + 16 * MB);     // 8MB   [4096][1024]
    bf16_t* Wih0R  = (bf16_t*)(ws + 24 * MB);     // 8MB
    bf16_t* Wlinb  = (bf16_t*)(ws + 32 * MB);     // 2MB
    bf16_t* zb     = (bf16_t*)(ws + 34 * MB);     // 2MB
    bf16_t* Xbuf   = (bf16_t*)(ws + 36 * MB);     // 8MB: X[2] each [1024][2048]
    float*  Gz0R   = (float*) (ws + 44 * MB);     // 16MB  [1024][4096]
    bf16_t* stash  = (bf16_t*)(ws + 60 * MB);     // 8MB: 4 x [1024][1024]
    float*  c0     = (float*) (ws + 68 * MB);     // 4MB
    float*  c1     = (float*) (ws + 72 * MB);     // 4MB
    float*  bias0R = (float*) (ws + 76 * MB);     // 16KB
    float*  bias1R = (float*) (ws + 76 * MB + 16384);
    bf16_t* X[2] = {Xbuf, Xbuf + (size_t)(1u << 21)};

    convR_f32_bf16<<<4096, 256, 0, stream>>>((const float4*)W_ih0, (bf16x4*)Wih0R);
    convR_f32_bf16<<<4096, 256, 0, stream>>>((const float4*)W_hh0, (bf16x4*)Whh0R);
    prep_wcatR<<<4096, 256, 0, stream>>>((const float4*)W_ih1, (const float4*)W_hh1, (bf16x4*)WcatR1);
    conv_f32_bf16<<<1024, 256, 0, stream>>>((const float4*)W_lin, (bf16x4*)Wlinb);
    prep_biasR<<<16, 256, 0, stream>>>(b_ih0, b_hh0, b_ih1, b_hh1, bias0R, bias1R);
    prep_init<<<4096, 256, 0, stream>>>(z, zb, X[0], c0, c1);

    // Gz0R = z @ W_ih0R^T + bias0R (reordered cols), f32
    gemm_bf16_nt<<<dim3(32, 8, 1), 512, 0, stream>>>(zb, 1024, 0, Wih0R, 1024, bias0R, Gz0R, 4096, 0, 1024);

    // fused0(0): X[0].x = H0[1] = cell0(Gz0R + z @ Whh0R^T, c0)
    {
        FusedArgs f0;
        f0.A = zb; f0.lda = 1024; f0.B = Whh0R; f0.add = Gz0R; f0.biasR = nullptr;
        f0.c = c0; f0.h1 = X[0]; f0.h1s = 2048; f0.h2 = nullptr; f0.h2s = 0; f0.K = 1024;
        fused_gemm_cell<<<dim3(32, 8, 1), 512, 0, stream>>>(f0, f0);
    }

    for (int t = 0; t < 4; ++t) {
        const int p = t & 1;
        FusedArgs a0;   // fused1(t): K=2048, reads X[p]=[H0[t+1]|H1[t]], writes H1[t+1]
        a0.A = X[p]; a0.lda = 2048; a0.B = WcatR1; a0.add = nullptr; a0.biasR = bias1R;
        a0.c = c1; a0.h1 = stash + (size_t)t * (1u << 20); a0.h1s = 1024;
        a0.h2 = (t < 3) ? X[p ^ 1] + 1024 : nullptr; a0.h2s = 2048; a0.K = 2048;
        if (t < 3) {
            FusedArgs a1;  // fused0(t+1): K=1024, reads X[p].x=H0[t+1], writes X[p^1].x=H0[t+2]
            a1.A = X[p]; a1.lda = 2048; a1.B = Whh0R; a1.add = Gz0R; a1.biasR = nullptr;
            a1.c = c0; a1.h1 = X[p ^ 1]; a1.h1s = 2048; a1.h2 = nullptr; a1.h2s = 0; a1.K = 1024;
            fused_gemm_cell<<<dim3(32, 8, 2), 512, 0, stream>>>(a0, a1);
        } else {
            fused_gemm_cell<<<dim3(32, 8, 1), 512, 0, stream>>>(a0, a0);
        }
    }

    // out[b][t][:] = H1[t+1] @ W_lin^T + b_lin, batched over t via grid.z
    gemm_bf16_nt<<<dim3(8, 8, 4), 512, 0, stream>>>(stash, 1024, (size_t)1 << 20, Wlinb, 1024, b_lin, out, 4096, 1024, 1024);
}

// Round 6
// 224.343 us; speedup vs baseline: 1.0196x; 1.0196x over previous
//
#include <hip/hip_runtime.h>
#include <hip/hip_bf16.h>
#include <cstdint>
#include <cstddef>

// LSTM fused pipeline, round 3.
// - cell fused into GEMM epilogue via gate-interleaved layout (j = 4n + gate)
// - combo dispatches: fused1(t) [K=2048] || fused0(t+1) [K=1024] -> 512 blocks, 2/CU
// - Gz0R = z @ W_ih0R^T + bias0R precomputed once (z constant across steps)
// - 2-phase double-buffered GEMM core, LDS swizzle via pre-swizzled global source

typedef __bf16 bf16_t;
typedef __bf16 bf16x8 __attribute__((ext_vector_type(8)));
typedef __bf16 bf16x4 __attribute__((ext_vector_type(4)));
typedef float f32x4 __attribute__((ext_vector_type(4)));

__device__ __forceinline__ void gload_lds16(const bf16_t* g, bf16_t* l) {
    __builtin_amdgcn_global_load_lds(
        (const __attribute__((address_space(1))) void*)g,
        (__attribute__((address_space(3))) void*)l,
        16, 0, 0);
}

__device__ __forceinline__ float sigmoid_f(float x) {
    return 1.f / (1.f + __expf(-x));
}
__device__ __forceinline__ float tanh_fast(float x) {
    const float t = __expf(2.f * x);
    return 1.f - 2.f / (t + 1.f);
}

// Shared GEMM core: C_tile(128x128) = A[brow:+128, :K] @ B[bcol:+128, :K]^T.
// block = 512 (8 waves, 2x4), wave = 64x32 = 4x2 frags. lsA/lsB: 2 bufs x 8192 bf16 each.
__device__ __forceinline__ void gemm_core(
    const bf16_t* __restrict__ A, int lda,
    const bf16_t* __restrict__ B, int ldb,
    int K, int brow, int bcol,
    bf16_t* lsA, bf16_t* lsB, f32x4 acc[4][2])
{
    const int tid  = threadIdx.x;
    const int lane = tid & 63;
    const int wave = tid >> 6;
    const int wm = (wave >> 2) * 64;
    const int wn = (wave & 3) * 32;
    const int srow = lane >> 3;                  // 0..7
    const int ssw  = ((lane & 7) ^ srow) * 8;    // pre-swizzled source col (rule #21)
    const int ch0  = wave * 2;
    const int nkt  = K >> 6;

    auto stage = [&](int buf, int ktel) {
#pragma unroll
        for (int it = 0; it < 2; ++it) {
            const int ch = ch0 + it;
            const int row = ch * 8 + srow;
            gload_lds16(A + (size_t)(brow + row) * lda + ktel + ssw, &lsA[buf * 8192 + ch * 512]);
            gload_lds16(B + (size_t)(bcol + row) * ldb + ktel + ssw, &lsB[buf * 8192 + ch * 512]);
        }
    };

    stage(0, 0);
    __syncthreads();

    const int fr  = lane & 15;
    const int g8  = (lane >> 4) * 8;
    const int rsw = (fr & 7) * 8;                // read-side swizzle XOR (elems)

    for (int kt = 0; kt < nkt; ++kt) {
        const int buf = kt & 1;
        if (kt + 1 < nkt) stage(buf ^ 1, (kt + 1) << 6);   // prefetch BEFORE compute
#pragma unroll
        for (int kk = 0; kk < 2; ++kk) {
            const int ko = (kk * 32 + g8) ^ rsw;
            bf16x8 af[4], bfv[2];
#pragma unroll
            for (int m = 0; m < 4; ++m)
                af[m] = *(const bf16x8*)&lsA[buf * 8192 + (wm + m * 16 + fr) * 64 + ko];
#pragma unroll
            for (int n = 0; n < 2; ++n)
                bfv[n] = *(const bf16x8*)&lsB[buf * 8192 + (wn + n * 16 + fr) * 64 + ko];
#pragma unroll
            for (int m = 0; m < 4; ++m)
#pragma unroll
                for (int n = 0; n < 2; ++n)
                    acc[m][n] = __builtin_amdgcn_mfma_f32_16x16x32_bf16(af[m], bfv[n], acc[m][n], 0, 0, 0);
        }
        __syncthreads();   // drains prefetch vmcnt + protects LDS
    }
}

// ---- plain GEMM (Gz0 + output linear): C = A@B^T + bias, f32 out ----
__global__ __launch_bounds__(512) void gemm_bf16_nt(
    const bf16_t* __restrict__ A, int lda, size_t sAz,
    const bf16_t* __restrict__ B, int ldb,
    const float* __restrict__ bias,
    float* __restrict__ C, int ldc, int czoff, int K)
{
    __shared__ __align__(16) bf16_t ls[32768];
    f32x4 acc[4][2] = {};
    const int brow = blockIdx.y * 128;
    const int bcol = blockIdx.x * 128;
    gemm_core(A + (size_t)blockIdx.z * sAz, lda, B, ldb, K, brow, bcol, ls, ls + 16384, acc);

    const int lane = threadIdx.x & 63;
    const int wave = threadIdx.x >> 6;
    const int wm = (wave >> 2) * 64;
    const int wn = (wave & 3) * 32;
    const int cr = (lane >> 4) * 4;
    const int cc = lane & 15;
    const size_t colz = (size_t)blockIdx.z * czoff;
#pragma unroll
    for (int n = 0; n < 2; ++n) {
        const int col = bcol + wn + n * 16 + cc;
        const float bv = bias ? bias[col] : 0.f;
#pragma unroll
        for (int m = 0; m < 4; ++m) {
            const int row0 = brow + wm + m * 16 + cr;
#pragma unroll
            for (int r = 0; r < 4; ++r)
                C[(size_t)(row0 + r) * ldc + colz + col] = acc[m][n][r] + bv;
        }
    }
}

// ---- fused GEMM + LSTM cell (gate-interleaved layout j = 4n + gate) ----
struct FusedArgs {
    const bf16_t* A;       // [1024][lda]
    const bf16_t* B;       // [4096][K] reordered rows
    const float*  add;     // f32 [1024][4096] reordered (Gz0R) or null
    const float*  biasR;   // f32 [4096] reordered or null
    float*        c;       // f32 [1024][1024] cell state (in/out)
    bf16_t*       h1; int h1s;   // h dest 1 (stride in elems)
    bf16_t*       h2; int h2s;   // h dest 2 or null
    int K; int lda;
};

__global__ __launch_bounds__(512, 4) void fused_gemm_cell(FusedArgs fa0, FusedArgs fa1)
{
    __shared__ __align__(16) float gsm[16384];   // 64KB: staging (bf16) then gates (f32)
    const FusedArgs fa = blockIdx.z ? fa1 : fa0;
    const int brow = blockIdx.y * 128;
    const int bcol = blockIdx.x * 128;

    f32x4 acc[4][2] = {};
    bf16_t* ls = (bf16_t*)gsm;
    gemm_core(fa.A, fa.lda, fa.B, fa.K, fa.K, brow, bcol, ls, ls + 16384, acc);
    // core ends with __syncthreads() and drained vmcnt -> LDS reusable

    const int tid  = threadIdx.x;
    const int lane = tid & 63;
    const int wave = tid >> 6;
    const int wm = (wave >> 2) * 64;
    const int wn = (wave & 3) * 32;
    const int cr = (lane >> 4) * 4;
    const int cc = lane & 15;
#pragma unroll
    for (int n = 0; n < 2; ++n)
#pragma unroll
        for (int m = 0; m < 4; ++m)
#pragma unroll
            for (int r = 0; r < 4; ++r)
                gsm[(wm + m * 16 + cr + r) * 128 + wn + n * 16 + cc] = acc[m][n][r];
    __syncthreads();

    // cell: 4096 (row, n) pairs, 8 per thread; gates at [row][4nn .. 4nn+3]
#pragma unroll
    for (int p = 0; p < 8; ++p) {
        const int idx = p * 512 + tid;
        const int rl = idx >> 5;          // 0..127
        const int nn = idx & 31;          // 0..31
        float4 gv = *(const float4*)&gsm[rl * 128 + nn * 4];
        const int grow = brow + rl;
        const int j0 = bcol + nn * 4;
        if (fa.add) {
            const float4 av = *(const float4*)&fa.add[(size_t)grow * 4096 + j0];
            gv.x += av.x; gv.y += av.y; gv.z += av.z; gv.w += av.w;
        }
        if (fa.biasR) {
            const float4 bv = *(const float4*)&fa.biasR[j0];
            gv.x += bv.x; gv.y += bv.y; gv.z += bv.z; gv.w += bv.w;
        }
        const int ng = j0 >> 2;           // global n
        const size_t ci = (size_t)grow * 1024 + ng;
        const float cn = sigmoid_f(gv.y) * fa.c[ci] + sigmoid_f(gv.x) * tanh_fast(gv.z);
        const float h  = sigmoid_f(gv.w) * tanh_fast(cn);
        fa.c[ci] = cn;
        const bf16_t hb = (bf16_t)h;
        fa.h1[(size_t)grow * fa.h1s + ng] = hb;
        if (fa.h2) fa.h2[(size_t)grow * fa.h2s + ng] = hb;
    }
}

// ---- prep kernels ----

// plain f32 -> bf16 (W_lin)
__global__ __launch_bounds__(256) void conv_f32_bf16(
    const float4* __restrict__ in, bf16x4* __restrict__ out)
{
    const int t = blockIdx.x * 256 + threadIdx.x;
    const float4 a = in[t];
    bf16x4 v = {(bf16_t)a.x, (bf16_t)a.y, (bf16_t)a.z, (bf16_t)a.w};
    out[t] = v;
}

// f32 [4096][1024] -> bf16 with row reorder j=4n+g <- g*1024+n
__global__ __launch_bounds__(256) void convR_f32_bf16(
    const float4* __restrict__ in, bf16x4* __restrict__ out)
{
    const int tid = blockIdx.x * 256 + threadIdx.x;   // 4096*256
    const int j = tid >> 8;
    const int col = tid & 255;
    const int g = j & 3, n = j >> 2;
    const float4 a = in[(g * 1024 + n) * 256 + col];
    bf16x4 v = {(bf16_t)a.x, (bf16_t)a.y, (bf16_t)a.z, (bf16_t)a.w};
    out[tid] = v;
}

// WcatR[4096][2048] = [W_ih1 | W_hh1] reordered rows j=4n+g
__global__ __launch_bounds__(256) void prep_wcatR(
    const float4* __restrict__ Wih, const float4* __restrict__ Whh, bf16x4* __restrict__ Wcat)
{
    const int tid = blockIdx.x * 256 + threadIdx.x;   // 4096*256
    const int j = tid >> 8;
    const int col = tid & 255;
    const int g = j & 3, n = j >> 2;
    const int src = (g * 1024 + n) * 256 + col;
    const float4 a = Wih[src];
    const float4 b = Whh[src];
    bf16x4 va = {(bf16_t)a.x, (bf16_t)a.y, (bf16_t)a.z, (bf16_t)a.w};
    bf16x4 vb = {(bf16_t)b.x, (bf16_t)b.y, (bf16_t)b.z, (bf16_t)b.w};
    Wcat[j * 512 + col]       = va;
    Wcat[j * 512 + 256 + col] = vb;
}

__global__ __launch_bounds__(256) void prep_biasR(
    const float* __restrict__ bih0, const float* __restrict__ bhh0,
    const float* __restrict__ bih1, const float* __restrict__ bhh1,
    float* __restrict__ b0R, float* __restrict__ b1R)
{
    const int j = blockIdx.x * 256 + threadIdx.x;     // 4096
    const int g = j & 3, n = j >> 2;
    b0R[j] = bih0[g * 1024 + n] + bhh0[g * 1024 + n];
    b1R[j] = bih1[g * 1024 + n] + bhh1[g * 1024 + n];
}

// zb = bf16(z); X0 h-slot = bf16(z); c0 = c1 = z
__global__ __launch_bounds__(256) void prep_init(
    const float* __restrict__ z, bf16_t* __restrict__ zb,
    bf16_t* __restrict__ X0, float* __restrict__ c0, float* __restrict__ c1)
{
    const int tid = blockIdx.x * 256 + threadIdx.x;   // 1M
    const int b = tid >> 10;
    const int n = tid & 1023;
    const float v = z[tid];
    const bf16_t h = (bf16_t)v;
    zb[tid] = h;
    X0[(size_t)b * 2048 + 1024 + n] = h;
    c0[tid] = v;
    c1[tid] = v;
}

extern "C" void kernel_launch(void* const* d_in, const int* in_sizes, int n_in,
                              void* d_out, int out_size, void* d_ws, size_t ws_size,
                              hipStream_t stream)
{
    const float* z     = (const float*)d_in[0];
    const float* W_ih0 = (const float*)d_in[1];
    const float* W_hh0 = (const float*)d_in[2];
    const float* b_ih0 = (const float*)d_in[3];
    const float* b_hh0 = (const float*)d_in[4];
    const float* W_ih1 = (const float*)d_in[5];
    const float* W_hh1 = (const float*)d_in[6];
    const float* b_ih1 = (const float*)d_in[7];
    const float* b_hh1 = (const float*)d_in[8];
    const float* W_lin = (const float*)d_in[9];
    const float* b_lin = (const float*)d_in[10];
    float* out = (float*)d_out;

    char* ws = (char*)d_ws;
    const size_t MB = 1u << 20;
    bf16_t* WcatR1 = (bf16_t*)(ws);               // 16MB  [4096][2048]
    bf16_t* Whh0R  = (bf16_t*)(ws + 16 * MB);     // 8MB   [4096][1024]
    bf16_t* Wih0R  = (bf16_t*)(ws + 24 * MB);     // 8MB
    bf16_t* Wlinb  = (bf16_t*)(ws + 32 * MB);     // 2MB
    bf16_t* zb     = (bf16_t*)(ws + 34 * MB);     // 2MB
    bf16_t* Xbuf   = (bf16_t*)(ws + 36 * MB);     // 8MB: X[2] each [1024][2048]
    float*  Gz0R   = (float*) (ws + 44 * MB);     // 16MB  [1024][4096]
    bf16_t* stash  = (bf16_t*)(ws + 60 * MB);     // 8MB: 4 x [1024][1024]
    float*  c0     = (float*) (ws + 68 * MB);     // 4MB
    float*  c1     = (float*) (ws + 72 * MB);     // 4MB
    float*  bias0R = (float*) (ws + 76 * MB);     // 16KB
    float*  bias1R = (float*) (ws + 76 * MB + 16384);
    bf16_t* X[2] = {Xbuf, Xbuf + (size_t)(1u << 21)};

    convR_f32_bf16<<<4096, 256, 0, stream>>>((const float4*)W_ih0, (bf16x4*)Wih0R);
    convR_f32_bf16<<<4096, 256, 0, stream>>>((const float4*)W_hh0, (bf16x4*)Whh0R);
    prep_wcatR<<<4096, 256, 0, stream>>>((const float4*)W_ih1, (const float4*)W_hh1, (bf16x4*)WcatR1);
    conv_f32_bf16<<<1024, 256, 0, stream>>>((const float4*)W_lin, (bf16x4*)Wlinb);
    prep_biasR<<<16, 256, 0, stream>>>(b_ih0, b_hh0, b_ih1, b_hh1, bias0R, bias1R);
    prep_init<<<4096, 256, 0, stream>>>(z, zb, X[0], c0, c1);

    // Gz0R = z @ W_ih0R^T + bias0R (reordered cols), f32
    gemm_bf16_nt<<<dim3(32, 8, 1), 512, 0, stream>>>(zb, 1024, 0, Wih0R, 1024, bias0R, Gz0R, 4096, 0, 1024);

    // fused0(0): X[0].x = H0[1] = cell0(Gz0R + z @ Whh0R^T, c0)
    {
        FusedArgs f0;
        f0.A = zb; f0.lda = 1024; f0.B = Whh0R; f0.add = Gz0R; f0.biasR = nullptr;
        f0.c = c0; f0.h1 = X[0]; f0.h1s = 2048; f0.h2 = nullptr; f0.h2s = 0; f0.K = 1024;
        fused_gemm_cell<<<dim3(32, 8, 1), 512, 0, stream>>>(f0, f0);
    }

    for (int t = 0; t < 4; ++t) {
        const int p = t & 1;
        FusedArgs a0;   // fused1(t): K=2048, reads X[p]=[H0[t+1]|H1[t]], writes H1[t+1]
        a0.A = X[p]; a0.lda = 2048; a0.B = WcatR1; a0.add = nullptr; a0.biasR = bias1R;
        a0.c = c1; a0.h1 = stash + (size_t)t * (1u << 20); a0.h1s = 1024;
        a0.h2 = (t < 3) ? X[p ^ 1] + 1024 : nullptr; a0.h2s = 2048; a0.K = 2048;
        if (t < 3) {
            FusedArgs a1;  // fused0(t+1): K=1024, reads X[p].x=H0[t+1], writes X[p^1].x=H0[t+2]
            a1.A = X[p]; a1.lda = 2048; a1.B = Whh0R; a1.add = Gz0R; a1.biasR = nullptr;
            a1.c = c0; a1.h1 = X[p ^ 1]; a1.h1s = 2048; a1.h2 = nullptr; a1.h2s = 0; a1.K = 1024;
            fused_gemm_cell<<<dim3(32, 8, 2), 512, 0, stream>>>(a0, a1);
        } else {
            fused_gemm_cell<<<dim3(32, 8, 1), 512, 0, stream>>>(a0, a0);
        }
    }

    // out[b][t][:] = H1[t+1] @ W_lin^T + b_lin, batched over t via grid.z
    gemm_bf16_nt<<<dim3(8, 8, 4), 512, 0, stream>>>(stash, 1024, (size_t)1 << 20, Wlinb, 1024, b_lin, out, 4096, 1024, 1024);
}

// Round 7
// 220.103 us; speedup vs baseline: 1.0392x; 1.0193x over previous
//
#include <hip/hip_runtime.h>
#include <hip/hip_bf16.h>
#include <cstdint>
#include <cstddef>

// LSTM fused pipeline, round 7.
// - job-array dispatches: up to 3 independent GEMM(+cell) jobs per launch
// - Wsum0 = W_ih0+W_hh0 makes t=0 layer-0 a single GEMM, parallel with Gz0R
// - lin(t) folded into combo(t+1)
// - single merged prep dispatch
// - XCD-aware tile ordering (same-B-panel tiles land on one XCD's L2)

typedef __bf16 bf16_t;
typedef __bf16 bf16x8 __attribute__((ext_vector_type(8)));
typedef __bf16 bf16x4 __attribute__((ext_vector_type(4)));
typedef float f32x4 __attribute__((ext_vector_type(4)));

__device__ __forceinline__ void gload_lds16(const bf16_t* g, bf16_t* l) {
    __builtin_amdgcn_global_load_lds(
        (const __attribute__((address_space(1))) void*)g,
        (__attribute__((address_space(3))) void*)l,
        16, 0, 0);
}

__device__ __forceinline__ float sigmoid_f(float x) {
    return 1.f / (1.f + __expf(-x));
}
__device__ __forceinline__ float tanh_fast(float x) {
    const float t = __expf(2.f * x);
    return 1.f - 2.f / (t + 1.f);
}

// Shared GEMM core: C_tile(128x128) = A[brow:+128, :K] @ B[bcol:+128, :K]^T.
// block = 512 (8 waves, 2x4), wave = 64x32 = 4x2 frags. lsA/lsB: 2 bufs x 8192 bf16 each.
__device__ __forceinline__ void gemm_core(
    const bf16_t* __restrict__ A, int lda,
    const bf16_t* __restrict__ B, int ldb,
    int K, int brow, int bcol,
    bf16_t* lsA, bf16_t* lsB, f32x4 acc[4][2])
{
    const int tid  = threadIdx.x;
    const int lane = tid & 63;
    const int wave = tid >> 6;
    const int wm = (wave >> 2) * 64;
    const int wn = (wave & 3) * 32;
    const int srow = lane >> 3;                  // 0..7
    const int ssw  = ((lane & 7) ^ srow) * 8;    // pre-swizzled source col (rule #21)
    const int ch0  = wave * 2;
    const int nkt  = K >> 6;

    auto stage = [&](int buf, int ktel) {
#pragma unroll
        for (int it = 0; it < 2; ++it) {
            const int ch = ch0 + it;
            const int row = ch * 8 + srow;
            gload_lds16(A + (size_t)(brow + row) * lda + ktel + ssw, &lsA[buf * 8192 + ch * 512]);
            gload_lds16(B + (size_t)(bcol + row) * ldb + ktel + ssw, &lsB[buf * 8192 + ch * 512]);
        }
    };

    stage(0, 0);
    __syncthreads();

    const int fr  = lane & 15;
    const int g8  = (lane >> 4) * 8;
    const int rsw = (fr & 7) * 8;                // read-side swizzle XOR (elems)

    for (int kt = 0; kt < nkt; ++kt) {
        const int buf = kt & 1;
        if (kt + 1 < nkt) stage(buf ^ 1, (kt + 1) << 6);   // prefetch BEFORE compute
#pragma unroll
        for (int kk = 0; kk < 2; ++kk) {
            const int ko = (kk * 32 + g8) ^ rsw;
            bf16x8 af[4], bfv[2];
#pragma unroll
            for (int m = 0; m < 4; ++m)
                af[m] = *(const bf16x8*)&lsA[buf * 8192 + (wm + m * 16 + fr) * 64 + ko];
#pragma unroll
            for (int n = 0; n < 2; ++n)
                bfv[n] = *(const bf16x8*)&lsB[buf * 8192 + (wn + n * 16 + fr) * 64 + ko];
#pragma unroll
            for (int m = 0; m < 4; ++m)
#pragma unroll
                for (int n = 0; n < 2; ++n)
                    acc[m][n] = __builtin_amdgcn_mfma_f32_16x16x32_bf16(af[m], bfv[n], acc[m][n], 0, 0, 0);
        }
        __syncthreads();   // drains prefetch vmcnt + protects LDS
    }
}

// ---- job descriptor ----
// mode 0: GEMM + LSTM cell epilogue (gate-interleaved cols j=4n+g).
// mode 1: GEMM + bias -> f32 C (ldc fixed 4096).
struct Job {
    const bf16_t* A;       // [1024][lda]
    const bf16_t* B;       // [N][K]
    const float*  add;     // f32 [1024][4096] (Gz0R) or null     (mode 0)
    const float*  bias;    // f32 [N-order of B] or null
    float*        c;       // f32 [1024][1024] cell state         (mode 0)
    bf16_t*       h1;      // h dest 1                            (mode 0)
    bf16_t*       h2;      // h dest 2 or null                    (mode 0)
    float*        C;       // f32 out, ldc=4096                   (mode 1)
    int lda, K, h1s, h2s, mode;
};

// All jobs: M=1024 (ny=8 tiles of 128). Tile order: x-major chunks per XCD.
__global__ __launch_bounds__(512, 4) void fused_multi(Job j0, Job j1, Job j2, int n0, int n01)
{
    __shared__ __align__(16) float gsm[16384];   // 64KB

    const int bid = blockIdx.x;
    Job ja; int local, n;
    if (bid < n0)        { ja = j0; local = bid;       n = n0; }
    else if (bid < n01)  { ja = j1; local = bid - n0;  n = n01 - n0; }
    else                 { ja = j2; local = bid - n01; n = (int)gridDim.x - n01; }

    // XCD-aware: bid%8 = XCD (bases are %8==0); give each XCD a contiguous
    // chunk of x-major tile space so same-B-panel tiles share an L2.
    const int q    = n >> 3;                          // n is a multiple of 8
    const int tile = (local & 7) * q + (local >> 3);
    const int bcol = (tile >> 3) * 128;
    const int brow = (tile & 7) * 128;

    f32x4 acc[4][2] = {};
    bf16_t* ls = (bf16_t*)gsm;
    gemm_core(ja.A, ja.lda, ja.B, ja.K, ja.K, brow, bcol, ls, ls + 16384, acc);
    // core ends with __syncthreads() and drained vmcnt -> LDS reusable

    const int tid  = threadIdx.x;
    const int lane = tid & 63;
    const int wave = tid >> 6;
    const int wm = (wave >> 2) * 64;
    const int wn = (wave & 3) * 32;
    const int cr = (lane >> 4) * 4;
    const int cc = lane & 15;

    if (ja.mode == 1) {
#pragma unroll
        for (int nn = 0; nn < 2; ++nn) {
            const int col = bcol + wn + nn * 16 + cc;
            const float bv = ja.bias ? ja.bias[col] : 0.f;
#pragma unroll
            for (int m = 0; m < 4; ++m) {
                const int row0 = brow + wm + m * 16 + cr;
#pragma unroll
                for (int r = 0; r < 4; ++r)
                    ja.C[(size_t)(row0 + r) * 4096 + col] = acc[m][nn][r] + bv;
            }
        }
        return;
    }

    // mode 0: stage acc tile to LDS, then cell epilogue
#pragma unroll
    for (int nn = 0; nn < 2; ++nn)
#pragma unroll
        for (int m = 0; m < 4; ++m)
#pragma unroll
            for (int r = 0; r < 4; ++r)
                gsm[(wm + m * 16 + cr + r) * 128 + wn + nn * 16 + cc] = acc[m][nn][r];
    __syncthreads();

#pragma unroll
    for (int p = 0; p < 8; ++p) {
        const int idx = p * 512 + tid;
        const int rl = idx >> 5;          // 0..127
        const int nn = idx & 31;          // 0..31
        float4 gv = *(const float4*)&gsm[rl * 128 + nn * 4];
        const int grow = brow + rl;
        const int j0c = bcol + nn * 4;
        if (ja.add) {
            const float4 av = *(const float4*)&ja.add[(size_t)grow * 4096 + j0c];
            gv.x += av.x; gv.y += av.y; gv.z += av.z; gv.w += av.w;
        }
        if (ja.bias) {
            const float4 bv = *(const float4*)&ja.bias[j0c];
            gv.x += bv.x; gv.y += bv.y; gv.z += bv.z; gv.w += bv.w;
        }
        const int ng = j0c >> 2;          // global n
        const size_t ci = (size_t)grow * 1024 + ng;
        const float cn = sigmoid_f(gv.y) * ja.c[ci] + sigmoid_f(gv.x) * tanh_fast(gv.z);
        const float h  = sigmoid_f(gv.w) * tanh_fast(cn);
        ja.c[ci] = cn;
        const bf16_t hb = (bf16_t)h;
        ja.h1[(size_t)grow * ja.h1s + ng] = hb;
        if (ja.h2) ja.h2[(size_t)grow * ja.h2s + ng] = hb;
    }
}

// ---- merged prep: all weight conversions + reorders + init in ONE dispatch ----
// thread ranges:
//  [0,       1048576): Wih0R, Whh0R, Wsum0R  (row reorder j=4n+g, reads both once)
//  [1048576, 2097152): WcatR1 = [Wih1|Whh1] reordered
//  [2097152, 2359296): Wlinb plain conv
//  [2359296, 2621440): zb, X0 h-slot, c0, c1
//  [2621440, 2622464): bias0R, bias1R (float4 per thread)
__global__ __launch_bounds__(256) void prep_all(
    const float* __restrict__ z,
    const float4* __restrict__ Wih0, const float4* __restrict__ Whh0,
    const float4* __restrict__ Wih1, const float4* __restrict__ Whh1,
    const float4* __restrict__ Wlin,
    const float* __restrict__ bih0, const float* __restrict__ bhh0,
    const float* __restrict__ bih1, const float* __restrict__ bhh1,
    bf16x4* __restrict__ Wih0R, bf16x4* __restrict__ Whh0R, bf16x4* __restrict__ Wsum0R,
    bf16x4* __restrict__ WcatR1, bf16x4* __restrict__ Wlinb,
    bf16_t* __restrict__ zb, bf16_t* __restrict__ X0,
    float* __restrict__ c0, float* __restrict__ c1,
    float* __restrict__ b0R, float* __restrict__ b1R)
{
    const int t = blockIdx.x * 256 + threadIdx.x;
    if (t < 1048576) {
        const int j = t >> 8, col = t & 255;
        const int g = j & 3, nn = j >> 2;
        const int src = (g * 1024 + nn) * 256 + col;
        const float4 a = Wih0[src];
        const float4 b = Whh0[src];
        bf16x4 va = {(bf16_t)a.x, (bf16_t)a.y, (bf16_t)a.z, (bf16_t)a.w};
        bf16x4 vb = {(bf16_t)b.x, (bf16_t)b.y, (bf16_t)b.z, (bf16_t)b.w};
        bf16x4 vs = {(bf16_t)(a.x + b.x), (bf16_t)(a.y + b.y),
                     (bf16_t)(a.z + b.z), (bf16_t)(a.w + b.w)};
        Wih0R[t] = va; Whh0R[t] = vb; Wsum0R[t] = vs;
    } else if (t < 2097152) {
        const int i = t - 1048576;
        const int j = i >> 8, col = i & 255;
        const int g = j & 3, nn = j >> 2;
        const int src = (g * 1024 + nn) * 256 + col;
        const float4 a = Wih1[src];
        const float4 b = Whh1[src];
        bf16x4 va = {(bf16_t)a.x, (bf16_t)a.y, (bf16_t)a.z, (bf16_t)a.w};
        bf16x4 vb = {(bf16_t)b.x, (bf16_t)b.y, (bf16_t)b.z, (bf16_t)b.w};
        WcatR1[j * 512 + col]       = va;
        WcatR1[j * 512 + 256 + col] = vb;
    } else if (t < 2359296) {
        const int i = t - 2097152;
        const float4 a = Wlin[i];
        bf16x4 v = {(bf16_t)a.x, (bf16_t)a.y, (bf16_t)a.z, (bf16_t)a.w};
        Wlinb[i] = v;
    } else if (t < 2621440) {
        const int i = t - 2359296;            // 0..262143, 4 elems each
        const int b = i >> 8, n4 = i & 255;
        const float4 v = ((const float4*)z)[i];
        bf16x4 hv = {(bf16_t)v.x, (bf16_t)v.y, (bf16_t)v.z, (bf16_t)v.w};
        ((bf16x4*)zb)[i] = hv;
        *(bf16x4*)(X0 + (size_t)b * 2048 + 1024 + n4 * 4) = hv;   // h1(0) = z
        ((float4*)c0)[i] = v;
        ((float4*)c1)[i] = v;
    } else if (t < 2622464) {
        const int nn = t - 2621440;           // 0..1023 -> j = 4nn+g
        float4 b0, b1;
        float* p0 = (float*)&b0; float* p1 = (float*)&b1;
#pragma unroll
        for (int g = 0; g < 4; ++g) {
            p0[g] = bih0[g * 1024 + nn] + bhh0[g * 1024 + nn];
            p1[g] = bih1[g * 1024 + nn] + bhh1[g * 1024 + nn];
        }
        ((float4*)b0R)[nn] = b0;
        ((float4*)b1R)[nn] = b1;
    }
}

extern "C" void kernel_launch(void* const* d_in, const int* in_sizes, int n_in,
                              void* d_out, int out_size, void* d_ws, size_t ws_size,
                              hipStream_t stream)
{
    const float* z     = (const float*)d_in[0];
    const float* W_ih0 = (const float*)d_in[1];
    const float* W_hh0 = (const float*)d_in[2];
    const float* b_ih0 = (const float*)d_in[3];
    const float* b_hh0 = (const float*)d_in[4];
    const float* W_ih1 = (const float*)d_in[5];
    const float* W_hh1 = (const float*)d_in[6];
    const float* b_ih1 = (const float*)d_in[7];
    const float* b_hh1 = (const float*)d_in[8];
    const float* W_lin = (const float*)d_in[9];
    const float* b_lin = (const float*)d_in[10];
    float* out = (float*)d_out;

    char* ws = (char*)d_ws;
    const size_t MB = 1u << 20;
    bf16_t* WcatR1 = (bf16_t*)(ws);               // 16MB [4096][2048]
    bf16_t* Whh0R  = (bf16_t*)(ws + 16 * MB);     // 8MB  [4096][1024]
    bf16_t* Wih0R  = (bf16_t*)(ws + 24 * MB);     // 8MB
    bf16_t* Wsum0R = (bf16_t*)(ws + 32 * MB);     // 8MB
    bf16_t* Wlinb  = (bf16_t*)(ws + 40 * MB);     // 2MB
    bf16_t* zb     = (bf16_t*)(ws + 42 * MB);     // 2MB
    bf16_t* Xbuf   = (bf16_t*)(ws + 44 * MB);     // 8MB: X[2] each [1024][2048]
    float*  Gz0R   = (float*) (ws + 52 * MB);     // 16MB [1024][4096]
    bf16_t* stash  = (bf16_t*)(ws + 68 * MB);     // 8MB: 4 x [1024][1024]
    float*  c0     = (float*) (ws + 76 * MB);     // 4MB
    float*  c1     = (float*) (ws + 80 * MB);     // 4MB
    float*  bias0R = (float*) (ws + 84 * MB);     // 16KB
    float*  bias1R = (float*) (ws + 84 * MB + 16384);
    bf16_t* X[2] = {Xbuf, Xbuf + (size_t)(1u << 21)};

    prep_all<<<10244, 256, 0, stream>>>(
        z, (const float4*)W_ih0, (const float4*)W_hh0,
        (const float4*)W_ih1, (const float4*)W_hh1, (const float4*)W_lin,
        b_ih0, b_hh0, b_ih1, b_hh1,
        (bf16x4*)Wih0R, (bf16x4*)Whh0R, (bf16x4*)Wsum0R,
        (bf16x4*)WcatR1, (bf16x4*)Wlinb,
        zb, X[0], c0, c1, bias0R, bias1R);

    Job empty = {};

    // D1: Gz0R = z@Wih0R^T + bias0R  ||  fused0(0): h0(1) = cell0(z@Wsum0R^T + bias0R)
    {
        Job gz = {};
        gz.A = zb; gz.lda = 1024; gz.B = Wih0R; gz.K = 1024;
        gz.bias = bias0R; gz.C = Gz0R; gz.mode = 1;
        Job f00 = {};
        f00.A = zb; f00.lda = 1024; f00.B = Wsum0R; f00.K = 1024;
        f00.bias = bias0R; f00.c = c0; f00.h1 = X[0]; f00.h1s = 2048; f00.mode = 0;
        fused_multi<<<512, 512, 0, stream>>>(gz, f00, empty, 256, 512);
    }

    // D2..D5: combo(t) = fused1(t) || fused0(t+1) (t<3) || lin(t-1) (t>=1)
    for (int t = 0; t < 4; ++t) {
        const int p = t & 1;
        Job a0 = {};   // fused1(t): K=2048, reads X[p]=[h0(t+1)|h1(t)], writes h1(t+1)
        a0.A = X[p]; a0.lda = 2048; a0.B = WcatR1; a0.K = 2048;
        a0.bias = bias1R; a0.c = c1;
        a0.h1 = stash + (size_t)t * (1u << 20); a0.h1s = 1024;
        if (t < 3) { a0.h2 = X[p ^ 1] + 1024; a0.h2s = 2048; }
        a0.mode = 0;

        Job a1 = {};   // fused0(t+1): K=1024, reads X[p] x-slot, writes X[p^1] x-slot
        if (t < 3) {
            a1.A = X[p]; a1.lda = 2048; a1.B = Whh0R; a1.K = 1024;
            a1.add = Gz0R; a1.c = c0; a1.h1 = X[p ^ 1]; a1.h1s = 2048; a1.mode = 0;
        }

        Job lj = {};   // lin(t-1): out[:, t-1, :] = stash(t-1)@Wlinb^T + b_lin
        if (t >= 1) {
            lj.A = stash + (size_t)(t - 1) * (1u << 20); lj.lda = 1024;
            lj.B = Wlinb; lj.K = 1024; lj.bias = b_lin;
            lj.C = out + (size_t)(t - 1) * 1024; lj.mode = 1;
        }

        if (t == 0)      fused_multi<<<512, 512, 0, stream>>>(a0, a1, empty, 256, 512);
        else if (t < 3)  fused_multi<<<576, 512, 0, stream>>>(a0, a1, lj, 256, 512);
        else             fused_multi<<<320, 512, 0, stream>>>(a0, lj, empty, 256, 320);
    }

    // D6: lin(3)
    {
        Job lj = {};
        lj.A = stash + (size_t)3 * (1u << 20); lj.lda = 1024;
        lj.B = Wlinb; lj.K = 1024; lj.bias = b_lin;
        lj.C = out + (size_t)3 * 1024; lj.mode = 1;
        fused_multi<<<64, 512, 0, stream>>>(lj, empty, empty, 64, 64);
    }
}